// Round 1
// baseline (674.838 us; speedup 1.0000x reference)
//
#include <hip/hip_runtime.h>

// ---------------- problem constants ----------------
#define NNODES 100000
#define NEDGES 1600000
#define KDIM 256          // IN
#define CDIM 256          // H*F
#define NHEAD 4
#define FDIM 64
#define NEG 0.05f

typedef short bf16x8 __attribute__((ext_vector_type(8)));   // 8 bf16 in 4 VGPRs
typedef float f32x4  __attribute__((ext_vector_type(4)));
typedef __attribute__((address_space(3))) void*       lds_vp;
typedef __attribute__((address_space(1))) const void* glb_cvp;

__device__ __forceinline__ unsigned short f2b(float x) {   // fp32 -> bf16 RNE
    unsigned int u = __float_as_uint(x);
    return (unsigned short)((u + 0x7FFFu + ((u >> 16) & 1u)) >> 16);
}
__device__ __forceinline__ float b2f(unsigned short b) {
    return __uint_as_float(((unsigned int)b) << 16);
}
__device__ __forceinline__ float lrelu(float x) { return x > 0.f ? x : NEG * x; }

// ---------------- fp32 -> bf16 converts ----------------
__global__ __launch_bounds__(256) void cvt_feat(const float* __restrict__ in,
                                                unsigned short* __restrict__ out)
{
    int i = (blockIdx.x * 256 + threadIdx.x) * 4;
    float4 v = *(const float4*)(in + i);
    ushort4 o;
    o.x = f2b(v.x); o.y = f2b(v.y); o.z = f2b(v.z); o.w = f2b(v.w);
    *(ushort4*)(out + i) = o;
}

__global__ __launch_bounds__(256) void cvt_w(const float* __restrict__ Wfc,
                                             const float* __restrict__ Wres,
                                             unsigned short* __restrict__ out)
{
    int i = (blockIdx.x * 256 + threadIdx.x) * 4;   // 131072 total
    float4 v = (i < 65536) ? *(const float4*)(Wfc + i)
                           : *(const float4*)(Wres + (i - 65536));
    ushort4 o;
    o.x = f2b(v.x); o.y = f2b(v.y); o.z = f2b(v.z); o.w = f2b(v.w);
    *(ushort4*)(out + i) = o;
}

// ---------------- bf16 MFMA dual GEMM + fused el/er epilogue ----------------
// XCD-affinity swizzle: the 4 ny-siblings of one row-block are spaced 8 apart
// in dispatch index (same XCD under round-robin) -> A-tile reused in XCD L2.
// For ny<2, each wave owns exactly one head's 64 columns, so el/er are
// computed from the fp32 accumulators and stored directly (no extra pass).
__global__ __launch_bounds__(256) void gemm_mfma(
    const unsigned short* __restrict__ featb,   // [N][256] bf16
    const unsigned short* __restrict__ Wb,      // [512][256] bf16
    const float* __restrict__ bias,
    const float* __restrict__ attn_l, const float* __restrict__ attn_r,
    unsigned short* __restrict__ fsb,           // [N][256] bf16
    float* __restrict__ rst,                    // [N][256] fp32
    float* __restrict__ el, float* __restrict__ er)
{
    const int b = blockIdx.x;
    const int grp = b >> 5, w32 = b & 31;
    const int bx = grp * 8 + (w32 & 7);
    const int ny = w32 >> 3;
    if (bx >= (NNODES + 127) / 128) return;

    __shared__ __align__(16) char smem[32768];
    char* sA = smem;
    char* sB = smem + 16384;

    const int tid = threadIdx.x;
    const int w = tid >> 6, l = tid & 63;
    const int wm = w & 1, wn = w >> 1;
    const int row0 = bx * 128;

    f32x4 acc[4][4];
#pragma unroll
    for (int tm = 0; tm < 4; ++tm)
#pragma unroll
        for (int tn = 0; tn < 4; ++tn) acc[tm][tn] = (f32x4)0.f;

    const int srow = tid >> 3;
    const int sslot = tid & 7;

    for (int k0 = 0; k0 < 256; k0 += 64) {
        if (k0) __syncthreads();
#pragma unroll
        for (int it = 0; it < 4; ++it) {
            int r = srow + it * 32;
            int gr = row0 + r; if (gr >= NNODES) gr = NNODES - 1;
            int kc = sslot ^ (r & 7);
            const unsigned short* g = featb + (size_t)gr * 256 + k0 + kc * 8;
            void* sp = sA + (it * 256 + w * 64) * 16;
            __builtin_amdgcn_global_load_lds((glb_cvp)g, (lds_vp)sp, 16, 0, 0);
        }
#pragma unroll
        for (int it = 0; it < 4; ++it) {
            int r = srow + it * 32;
            int kc = sslot ^ (r & 7);
            const unsigned short* g = Wb + (size_t)(ny * 128 + r) * 256 + k0 + kc * 8;
            void* sp = sB + (it * 256 + w * 64) * 16;
            __builtin_amdgcn_global_load_lds((glb_cvp)g, (lds_vp)sp, 16, 0, 0);
        }
        __syncthreads();

        const int quad = l >> 4;
#pragma unroll
        for (int kk = 0; kk < 2; ++kk) {
            const int kc = kk * 4 + quad;
            bf16x8 af[4], bq[4];
#pragma unroll
            for (int tm = 0; tm < 4; ++tm) {
                int m = wm * 64 + tm * 16 + (l & 15);
                af[tm] = *(const bf16x8*)(sA + m * 128 + ((kc ^ (m & 7)) * 16));
            }
#pragma unroll
            for (int tn = 0; tn < 4; ++tn) {
                int n = wn * 64 + tn * 16 + (l & 15);
                bq[tn] = *(const bf16x8*)(sB + n * 128 + ((kc ^ (n & 7)) * 16));
            }
#pragma unroll
            for (int tm = 0; tm < 4; ++tm)
#pragma unroll
                for (int tn = 0; tn < 4; ++tn)
                    acc[tm][tn] = __builtin_amdgcn_mfma_f32_16x16x32_bf16(
                        af[tm], bq[tn], acc[tm][tn], 0, 0, 0);
        }
    }

    const int quad = l >> 4, c15 = l & 15;
    if (ny < 2) {
        // ---- fsb stores ----
#pragma unroll
        for (int tm = 0; tm < 4; ++tm) {
            int rb = row0 + wm * 64 + tm * 16 + quad * 4;
#pragma unroll
            for (int tn = 0; tn < 4; ++tn) {
                int cg = ny * 128 + wn * 64 + tn * 16 + c15;
#pragma unroll
                for (int reg = 0; reg < 4; ++reg) {
                    int r = rb + reg;
                    if (r < NNODES) fsb[(size_t)r * 256 + cg] = f2b(acc[tm][tn][reg]);
                }
            }
        }
        // ---- fused el/er: this wave owns head hh's full 64 columns ----
        const int hh = ny * 2 + wn;
        float alv[4], arv[4];
#pragma unroll
        for (int tn = 0; tn < 4; ++tn) {
            alv[tn] = attn_l[hh * 64 + tn * 16 + c15];
            arv[tn] = attn_r[hh * 64 + tn * 16 + c15];
        }
#pragma unroll
        for (int tm = 0; tm < 4; ++tm) {
#pragma unroll
            for (int reg = 0; reg < 4; ++reg) {
                float pl = 0.f, pr = 0.f;
#pragma unroll
                for (int tn = 0; tn < 4; ++tn) {
                    float v = acc[tm][tn][reg];
                    pl = fmaf(v, alv[tn], pl);
                    pr = fmaf(v, arv[tn], pr);
                }
#pragma unroll
                for (int d = 1; d < 16; d <<= 1) {
                    pl += __shfl_xor(pl, d);
                    pr += __shfl_xor(pr, d);
                }
                if (c15 == 0) {
                    int r = row0 + wm * 64 + tm * 16 + quad * 4 + reg;
                    if (r < NNODES) {
                        el[r * NHEAD + hh] = pl;
                        er[r * NHEAD + hh] = pr;
                    }
                }
            }
        }
    } else {
#pragma unroll
        for (int tm = 0; tm < 4; ++tm) {
            int rb = row0 + wm * 64 + tm * 16 + quad * 4;
#pragma unroll
            for (int tn = 0; tn < 4; ++tn) {
                int co = (ny - 2) * 128 + wn * 64 + tn * 16 + c15;
                float b2 = bias[co];
#pragma unroll
                for (int reg = 0; reg < 4; ++reg) {
                    int r = rb + reg;
                    if (r < NNODES) rst[(size_t)r * 256 + co] = acc[tm][tn][reg] + b2;
                }
            }
        }
    }
}

// ---------------- CSR build (order-free grouping by dst) ----------------
__global__ __launch_bounds__(256) void count_kernel(const int* __restrict__ dst,
                                                    int* __restrict__ cnt)
{
    int e = blockIdx.x * 256 + threadIdx.x;
    if (e < NEDGES) atomicAdd(&cnt[dst[e]], 1);
}

// Wave-aggregated allocation: 64-lane inclusive shfl scan, ONE atomic per
// wave instead of one per thread (100K same-address atomics -> 1563).
__global__ __launch_bounds__(256) void offset_kernel(const int* __restrict__ cnt,
                                                     int* __restrict__ off,
                                                     int* __restrict__ cursor,
                                                     int* __restrict__ total)
{
    int n = blockIdx.x * 256 + threadIdx.x;
    int lane = threadIdx.x & 63;
    int c = (n < NNODES) ? cnt[n] : 0;
    int incl = c;
#pragma unroll
    for (int d = 1; d < 64; d <<= 1) {
        int t = __shfl_up(incl, d);
        if (lane >= d) incl += t;
    }
    int wsum = __shfl(incl, 63);
    int base = 0;
    if (lane == 0) base = atomicAdd(total, wsum);
    base = __shfl(base, 0);
    if (n < NNODES) {
        int o = base + incl - c;
        off[n] = o;
        cursor[n] = o;
    }
}

__global__ __launch_bounds__(256) void scatter_kernel(const int* __restrict__ dst,
                                                      int* __restrict__ cursor,
                                                      int* __restrict__ perm)
{
    int e = blockIdx.x * 256 + threadIdx.x;
    if (e < NEDGES) {
        int p = atomicAdd(&cursor[dst[e]], 1);
        perm[p] = e;
    }
}

// ---------------- agg: one wave per dst node ----------------
// Sweep 2 inner loop: sj broadcast via v_readlane from register (no LDS
// round-trip), a via broadcast ds_read, saddr-form 8B gather, unroll 8 for
// more loads in flight. a_out is written directly from the normalized
// per-edge coefficient already in registers (aout kernel eliminated).
__global__ __launch_bounds__(256) void agg_kernel(
    const int* __restrict__ src, const int* __restrict__ perm,
    const int* __restrict__ off, const int* __restrict__ cnt,
    const float* __restrict__ el, const float* __restrict__ er,
    const unsigned short* __restrict__ fsb,
    float* __restrict__ rst,
    float* __restrict__ a_out)
{
    const int tid = threadIdx.x;
    const int wv = tid >> 6, lane = tid & 63;
    const int n = blockIdx.x * 4 + wv;
    const int deg = cnt[n];
    if (deg == 0) return;              // rst keeps residual
    const int o0 = off[n];
    const int h = lane >> 4;

    __shared__ __align__(16) float a_sh[4][64][4];
    float* aw = &a_sh[wv][0][0];

    const float4 er4 = *(const float4*)(er + (size_t)n * NHEAD);

    // ---- sweep 1: online (m, s) ----
    float4 m = make_float4(-1e30f, -1e30f, -1e30f, -1e30f);
    float4 s = make_float4(0.f, 0.f, 0.f, 0.f);
    int s0_save = 0, e0_save = 0; float4 l0_save = m;

    for (int base = 0; base < deg; base += 64) {
        int i = base + lane;
        bool valid = i < deg;
        int e = perm[o0 + (valid ? i : deg - 1)];
        int sidx = src[e];
        float4 ev = *(const float4*)(el + (size_t)sidx * NHEAD);
        float4 l;
        l.x = lrelu(ev.x + er4.x); l.y = lrelu(ev.y + er4.y);
        l.z = lrelu(ev.z + er4.z); l.w = lrelu(ev.w + er4.w);
        if (base == 0) { s0_save = sidx; e0_save = e; l0_save = l; }
        float mn;
        mn = fmaxf(m.x, l.x); s.x = s.x * __expf(m.x - mn) + (valid ? __expf(l.x - mn) : 0.f); m.x = mn;
        mn = fmaxf(m.y, l.y); s.y = s.y * __expf(m.y - mn) + (valid ? __expf(l.y - mn) : 0.f); m.y = mn;
        mn = fmaxf(m.z, l.z); s.z = s.z * __expf(m.z - mn) + (valid ? __expf(l.z - mn) : 0.f); m.z = mn;
        mn = fmaxf(m.w, l.w); s.w = s.w * __expf(m.w - mn) + (valid ? __expf(l.w - mn) : 0.f); m.w = mn;
    }
#pragma unroll
    for (int d = 32; d > 0; d >>= 1) {
        float mo, so, mn;
        mo = __shfl_xor(m.x, d); so = __shfl_xor(s.x, d);
        mn = fmaxf(m.x, mo); s.x = s.x * __expf(m.x - mn) + so * __expf(mo - mn); m.x = mn;
        mo = __shfl_xor(m.y, d); so = __shfl_xor(s.y, d);
        mn = fmaxf(m.y, mo); s.y = s.y * __expf(m.y - mn) + so * __expf(mo - mn); m.y = mn;
        mo = __shfl_xor(m.z, d); so = __shfl_xor(s.z, d);
        mn = fmaxf(m.z, mo); s.z = s.z * __expf(m.z - mn) + so * __expf(mo - mn); m.z = mn;
        mo = __shfl_xor(m.w, d); so = __shfl_xor(s.w, d);
        mn = fmaxf(m.w, mo); s.w = s.w * __expf(m.w - mn) + so * __expf(mo - mn); m.w = mn;
    }
    float4 inv;
    inv.x = 1.f / fmaxf(s.x, 1e-20f);
    inv.y = 1.f / fmaxf(s.y, 1e-20f);
    inv.z = 1.f / fmaxf(s.z, 1e-20f);
    inv.w = 1.f / fmaxf(s.w, 1e-20f);

    // ---- sweep 2: register-broadcast src + LDS-staged a + saddr gather ----
    float4 acc = make_float4(0.f, 0.f, 0.f, 0.f);
    const int laneoff = lane << 2;          // ushort index; 8B per lane
    for (int base = 0; base < deg; base += 64) {
        int i = base + lane;
        bool valid = i < deg;
        int sidx, e; float4 l;
        if (base == 0) { sidx = s0_save; e = e0_save; l = l0_save; }
        else {
            e = perm[o0 + (valid ? i : deg - 1)];
            sidx = src[e];
            float4 ev = *(const float4*)(el + (size_t)sidx * NHEAD);
            l.x = lrelu(ev.x + er4.x); l.y = lrelu(ev.y + er4.y);
            l.z = lrelu(ev.z + er4.z); l.w = lrelu(ev.w + er4.w);
        }
        float4 a;
        a.x = valid ? __expf(l.x - m.x) * inv.x : 0.f;
        a.y = valid ? __expf(l.y - m.y) * inv.y : 0.f;
        a.z = valid ? __expf(l.z - m.z) * inv.z : 0.f;
        a.w = valid ? __expf(l.w - m.w) * inv.w : 0.f;
        *(float4*)(aw + (lane << 2)) = a;   // wave-synchronous staging

        if (valid) *(float4*)(a_out + (size_t)e * NHEAD) = a;   // fused a_out

        int nc = min(64, deg - base);
#pragma unroll 8
        for (int j = 0; j < nc; ++j) {
            int sj = __builtin_amdgcn_readlane(sidx, j);       // reg -> SGPR
            float av = aw[(j << 2) + h];                       // broadcast ds_read
            const unsigned short* rp = fsb + ((size_t)(unsigned)sj << 8) + laneoff;
            uint2 p = *(const uint2*)rp;                       // saddr + lane voff
            acc.x = fmaf(av, __uint_as_float(p.x << 16), acc.x);
            acc.y = fmaf(av, __uint_as_float(p.x & 0xffff0000u), acc.y);
            acc.z = fmaf(av, __uint_as_float(p.y << 16), acc.z);
            acc.w = fmaf(av, __uint_as_float(p.y & 0xffff0000u), acc.w);
        }
    }
    size_t ro = (size_t)n * 256 + (lane << 2);
    float4 r = *(float4*)(rst + ro);
    r.x += acc.x; r.y += acc.y; r.z += acc.z; r.w += acc.w;
    *(float4*)(rst + ro) = r;
}

// ---------------- launch ----------------
extern "C" void kernel_launch(void* const* d_in, const int* in_sizes, int n_in,
                              void* d_out, int out_size, void* d_ws, size_t ws_size,
                              hipStream_t stream) {
    const float* feat   = (const float*)d_in[0];
    const int*   src    = (const int*)d_in[1];
    const int*   dst    = (const int*)d_in[2];
    const float* Wfc    = (const float*)d_in[3];
    const float* attn_l = (const float*)d_in[4];
    const float* attn_r = (const float*)d_in[5];
    const float* Wres   = (const float*)d_in[6];
    const float* bias   = (const float*)d_in[7];

    float* rst   = (float*)d_out;                              // N*256
    float* a_out = (float*)d_out + (size_t)NNODES * CDIM;      // E*4

    unsigned short* featb = (unsigned short*)d_ws;             // N*256 bf16
    unsigned short* fsb   = featb + (size_t)NNODES * CDIM;     // N*256 bf16
    unsigned short* Wb    = fsb + (size_t)NNODES * CDIM;       // 512*256 bf16
    float* el      = (float*)(Wb + 512 * 256);                 // N*4
    float* er      = el + (size_t)NNODES * NHEAD;              // N*4
    int* cnt    = (int*)(er + (size_t)NNODES * NHEAD);         // N
    int* off    = cnt + NNODES;                                // N
    int* cursor = off + NNODES;                                // N
    int* total  = cursor + NNODES;                             // 4
    int* perm   = total + 4;                                   // E

    hipMemsetAsync(cnt, 0, NNODES * sizeof(int), stream);
    hipMemsetAsync(total, 0, 4 * sizeof(int), stream);

    cvt_feat<<<(NNODES * CDIM) / (256 * 4), 256, 0, stream>>>(feat, featb);
    cvt_w<<<(512 * 256) / (256 * 4), 256, 0, stream>>>(Wfc, Wres, Wb);

    // 782 row-blocks -> 98 groups of 8 -> grid 98*32 = 3136 (tail guarded)
    gemm_mfma<<<3136, 256, 0, stream>>>(featb, Wb, bias, attn_l, attn_r,
                                        fsb, rst, el, er);

    count_kernel<<<(NEDGES + 255) / 256, 256, 0, stream>>>(dst, cnt);
    offset_kernel<<<(NNODES + 255) / 256, 256, 0, stream>>>(cnt, off, cursor, total);
    scatter_kernel<<<(NEDGES + 255) / 256, 256, 0, stream>>>(dst, cursor, perm);

    agg_kernel<<<NNODES / 4, 256, 0, stream>>>(src, perm, off, cnt, el, er,
                                               fsb, rst, a_out);
}